// Round 15
// baseline (408.927 us; speedup 1.0000x reference)
//
#include <hip/hip_runtime.h>
#include <hip/hip_bf16.h>
#include <stdint.h>

// ---------------------------------------------------------------------------
// Decoder (teacher-forced, state never advances):
//   gates = x @ W_ih^T + (h0 @ W_hh^T + b_ih + b_hh)  (broadcast over t)
//   i,f,g,o = split(gates); c' = sig(f)*c0 + sig(i)*tanh(g); h' = sig(o)*tanh(c')
//   out = h' @ fc_w^T + fc_b
// Sizes: B=64, T=1024, D=513, H=512, 4H=2048.  M = B*T = 65536.
// R14: gemm1 -> 256x256 tile, 1024 thr / 16 waves (4Mx4N, wave 64x64),
//     BK=32, 3x32KB LDS, R9-rotated race-free schedule (reads -> lgkm drain
//     -> stage(kt+2) -> vmcnt(2) -> barrier -> MFMA). Halves L2 ingest and
//     LDS writes per MFMA vs 128-wide tiles; 4 waves/SIMD in-block TLP.
//     MFMA pipe becomes the longest pole (model: 1030 vs LDS 750 vs L2 571).
//     prep (R13 fused) and gemm2 (R7 core) unchanged.
// ---------------------------------------------------------------------------

typedef __bf16 bf16x8 __attribute__((ext_vector_type(8)));
typedef float f32x4 __attribute__((ext_vector_type(4)));

#define MFMA_BF16 __builtin_amdgcn_mfma_f32_16x16x32_bf16

__device__ __forceinline__ void gld16(const void* gptr, void* lptr) {
  __builtin_amdgcn_global_load_lds(
      (const __attribute__((address_space(1))) void*)gptr,
      (__attribute__((address_space(3))) void*)lptr, 16, 0, 0);
}

__device__ __forceinline__ float fsigm(float x) {
  x = fminf(fmaxf(x, -30.f), 30.f);
  return __frcp_rn(1.f + __expf(-x));
}
__device__ __forceinline__ float ftanh(float x) {
  x = fminf(fmaxf(x, -15.f), 15.f);
  const float e = __expf(2.f * x);
  return (e - 1.f) * __frcp_rn(e + 1.f);
}

// --------------------------- fused prep (R13, unchanged) --------------------
__global__ __launch_bounds__(256) void prep_kernel(
    const float* __restrict__ x, const float* __restrict__ Wih,
    const float* __restrict__ fcw, const float* __restrict__ h0,
    const float* __restrict__ Whh, const float* __restrict__ bih,
    const float* __restrict__ bhh, __bf16* __restrict__ xbf,
    __bf16* __restrict__ wpk, __bf16* __restrict__ fwbf,
    float* __restrict__ hbias) {
  const int bid = blockIdx.x;
  const int t = threadIdx.x;

  if (bid < 2048) {  // ---- pack_wih
    const int p = bid;
    const int g = (p >> 4) & 3;
    const int h = ((p >> 6) << 4) + (p & 15);
    const float* src = Wih + (size_t)(g * 512 + h) * 513;
    for (int c = t * 2; c < 544; c += 512) {
      float v0 = (c < 513) ? src[c] : 0.f;
      float v1 = (c + 1 < 513) ? src[c + 1] : 0.f;
      union { __bf16 hh[2]; uint32_t u; } pk;
      pk.hh[0] = (__bf16)v0;
      pk.hh[1] = (__bf16)v1;
      *(uint32_t*)&wpk[(size_t)p * 544 + c] = pk.u;
    }
  } else if (bid < 2688) {  // ---- pack_fcw
    const int r = bid - 2048;
    const bool rv = r < 513;
    const float* src = fcw + (size_t)r * 512;
    for (int c = t * 2; c < 512; c += 512) {
      float v0 = rv ? src[c] : 0.f;
      float v1 = rv ? src[c + 1] : 0.f;
      union { __bf16 hh[2]; uint32_t u; } pk;
      pk.hh[0] = (__bf16)v0;
      pk.hh[1] = (__bf16)v1;
      *(uint32_t*)&fwbf[(size_t)r * 512 + c] = pk.u;
    }
  } else if (bid < 35456) {  // ---- hbias
    const int hb_bid = bid - 2688;
    const int w = t >> 6, l = t & 63;
    const int b = hb_bid >> 9;
    const int g = ((hb_bid & 511) << 2) | w;
    const float* hr = h0 + b * 512;
    const float* wr = Whh + (size_t)g * 512;
    float s = 0.f;
#pragma unroll
    for (int h = 0; h < 512; h += 64) s = fmaf(hr[h + l], wr[h + l], s);
#pragma unroll
    for (int off = 32; off; off >>= 1) s += __shfl_down(s, off);
    if (l == 0) hbias[b * 2048 + g] = s + bih[g] + bhh[g];
  } else {  // ---- pack_x
    const int r = bid - 35456;
    const float* src = x + (size_t)r * 513;
    for (int c = t * 2; c < 544; c += 512) {
      float v0 = (c < 513) ? src[c] : 0.f;
      float v1 = (c + 1 < 513) ? src[c + 1] : 0.f;
      union { __bf16 hh[2]; uint32_t u; } pk;
      pk.hh[0] = (__bf16)v0;
      pk.hh[1] = (__bf16)v1;
      *(uint32_t*)&xbf[(size_t)r * 544 + c] = pk.u;
    }
  }
}

// --------------------------- 256x256 16-wave core (new) ---------------------
// Tile 256x256, BK=32, 16 waves (4M x 4N), per-wave 64x64 (acc[4][4]).
// LDS: 3 buffers x (A 16KB + B 16KB) = 96KB -> 1 block/CU (16 waves,
// 4 waves/SIMD in-block TLP). Rotated schedule per round kt:
//   reads(kt) from buf kt%3 | lgkmcnt(0) drain | stage(kt+2)->(kt+2)%3
//   | vmcnt(2) (tile kt+1's 2 loads landed) | barrier | setprio 16 MFMA.
// Race-free: reads of buf b drain before round-kt barrier; b restaged only
// at round kt+1 after all waves crossed that barrier.
// Staging: wave w stages A subtile w (1 gld16) + B subtile w (1 gld16).
// Subtile = 16 rows x 32 k fragment-ordered: gld16 dest and ds_read are
// identity (base + lane*16) -> 0 bank conflicts.
template <int NKT, int KSTR>
__device__ __forceinline__ void gemm_core16(
    const __bf16* __restrict__ A, const __bf16* __restrict__ B,
    size_t m0, int n0, char* lds, f32x4 (&acc)[4][4],
    int wid, int l, int wm, int wn) {
  const int lr = l & 15, lq = l >> 4;
  const __bf16* ag = A + (m0 + wid * 16 + lr) * KSTR + lq * 8;
  const __bf16* bg = B + (size_t)(n0 + wid * 16 + lr) * KSTR + lq * 8;
  const int sdA = wid << 10;                    // A subtile wid
  const int sdB = 16384 + (wid << 10);          // B subtile wid
  const int ra = (wm << 12) + l * 16;           // A read: subtile wm*4+mi
  const int rbB = 16384 + (wn << 12) + l * 16;  // B read: subtile wn*4+ni

  // prologue: stage K-tiles 0,1 into buffers 0,1
#pragma unroll
  for (int p = 0; p < 2; ++p) {
    char* base = lds + p * 32768;
    gld16(ag + p * 32, base + sdA);
    gld16(bg + p * 32, base + sdB);
  }
  asm volatile("s_waitcnt vmcnt(2)" ::: "memory");  // tile-0 landed
  __builtin_amdgcn_s_barrier();

#pragma unroll
  for (int kt = 0; kt < NKT; ++kt) {
    const char* rbase = lds + (kt % 3) * 32768;
    // phase 1: fragment reads for THIS tile
    bf16x8 af[4], bq[4];
#pragma unroll
    for (int i = 0; i < 4; ++i)
      af[i] = *(const bf16x8*)(rbase + ra + i * 1024);
#pragma unroll
    for (int i = 0; i < 4; ++i)
      bq[i] = *(const bf16x8*)(rbase + rbB + i * 1024);
    asm volatile("s_waitcnt lgkmcnt(0)" ::: "memory");  // drain BEFORE barrier
    __builtin_amdgcn_sched_barrier(0);
    // phase 2: stage tile kt+2
    if (kt + 2 < NKT) {
      char* wbase = lds + ((kt + 2) % 3) * 32768;
      const int kof = (kt + 2) * 32;
      gld16(ag + kof, wbase + sdA);
      gld16(bg + kof, wbase + sdB);
      asm volatile("s_waitcnt vmcnt(2)" ::: "memory");  // tile kt+1 landed
    } else if (kt + 1 < NKT) {
      asm volatile("s_waitcnt vmcnt(0)" ::: "memory");  // tail
    }
    asm volatile("" ::: "memory");
    __builtin_amdgcn_s_barrier();
    // phase 3: MFMA cluster, zero outstanding waits
    __builtin_amdgcn_s_setprio(1);
#pragma unroll
    for (int mi = 0; mi < 4; ++mi)
#pragma unroll
      for (int ni = 0; ni < 4; ++ni)
        acc[mi][ni] = MFMA_BF16(af[mi], bq[ni], acc[mi][ni], 0, 0, 0);
    __builtin_amdgcn_s_setprio(0);
  }
}

// --------------------------- GEMM1 + LSTM cell (256x256) --------------------
// A = xbf [65536 x 544], B = wpk [2048 x 544] gate-interleaved.
// grid 2048 = 256 m-tiles x 8 n-tiles. 1024 threads.
__global__ __launch_bounds__(1024, 4) void gemm1_kernel(
    const __bf16* __restrict__ xbf, const __bf16* __restrict__ wpk,
    const float* __restrict__ hbias, const float* __restrict__ c0,
    __bf16* __restrict__ hnew) {
  const int t = threadIdx.x, wid = t >> 6, l = t & 63;
  const int wm = wid >> 2, wn = wid & 3;
  const int bid = blockIdx.x;
  const int swz = (bid & 7) * 256 + (bid >> 3);  // XCD-contiguous
  const size_t m0 = (size_t)(swz >> 3) << 8;
  const int n0 = (swz & 7) << 8;

  __shared__ __align__(16) char lds[98304];

  f32x4 acc[4][4];
#pragma unroll
  for (int mi = 0; mi < 4; ++mi)
#pragma unroll
    for (int ni = 0; ni < 4; ++ni) acc[mi][ni] = (f32x4){0.f, 0.f, 0.f, 0.f};

  gemm_core16<17, 544>(xbf, wpk, m0, n0, lds, acc, wid, l, wm, wn);

  // lane's packed col p = n0 + wn*64 + ni*16 + lr -> gate = ni,
  // h = (n0/64 + wn)*16 + lr. All 4 gates lane-local.
  const int lr = l & 15, lq = l >> 4;
  const int hcol = (((n0 >> 6) + wn) << 4) + lr;
  const int b = (int)(m0 >> 10);  // 256-row block fully inside one batch row
  const float hb0 = hbias[b * 2048 + hcol];
  const float hb1 = hbias[b * 2048 + 512 + hcol];
  const float hb2 = hbias[b * 2048 + 1024 + hcol];
  const float hb3 = hbias[b * 2048 + 1536 + hcol];
  const float c0v = c0[b * 512 + hcol];
#pragma unroll
  for (int mi = 0; mi < 4; ++mi) {
#pragma unroll
    for (int r = 0; r < 4; ++r) {
      const size_t m = m0 + wm * 64 + mi * 16 + lq * 4 + r;
      const float gi = acc[mi][0][r] + hb0;
      const float gf = acc[mi][1][r] + hb1;
      const float gg = acc[mi][2][r] + hb2;
      const float go = acc[mi][3][r] + hb3;
      const float cn = fsigm(gf) * c0v + fsigm(gi) * ftanh(gg);
      hnew[m * 512 + hcol] = (__bf16)(fsigm(go) * ftanh(cn));
    }
  }
}

// --------------------------- R7 core: 256x128, 8 waves (unchanged) ----------
template <int NKT, int KSTR>
__device__ __forceinline__ void gemm_core8(
    const __bf16* __restrict__ A, const __bf16* __restrict__ B,
    size_t m0, int n0, char* lds, f32x4 (&acc)[4][4],
    int wid, int l, int wm, int wc) {
  const int lr = l & 15, lq = l >> 4;
  const __bf16* ag = A + (m0 + wid * 16 + lr) * KSTR + lq * 8;
  const __bf16* ag2 = ag + (size_t)128 * KSTR;
  const __bf16* bg = B + (size_t)(n0 + wid * 16 + lr) * KSTR + lq * 8;
  const int sdA = wid << 10;
  const int sdB = 16384 + (wid << 10);
  const int ra = (wm << 12) + l * 16;
  const int rbB = 16384 + (wc << 12) + l * 16;

#pragma unroll
  for (int p = 0; p < 2; ++p) {
    char* base = lds + p * 24576;
    gld16(ag + p * 32, base + sdA);
    gld16(ag2 + p * 32, base + sdA + 8192);
    gld16(bg + p * 32, base + sdB);
  }
  asm volatile("s_waitcnt vmcnt(3)" ::: "memory");
  __builtin_amdgcn_s_barrier();

#pragma unroll
  for (int kt = 0; kt < NKT; ++kt) {
    char* rbase = lds + (kt % 3) * 24576;
    if (kt + 2 < NKT) {
      char* wbase = lds + ((kt + 2) % 3) * 24576;
      const int kof = (kt + 2) * 32;
      gld16(ag + kof, wbase + sdA);
      gld16(ag2 + kof, wbase + sdA + 8192);
      gld16(bg + kof, wbase + sdB);
    }
    bf16x8 af[4], bq[4];
#pragma unroll
    for (int i = 0; i < 4; ++i)
      af[i] = *(const bf16x8*)(rbase + ra + i * 1024);
#pragma unroll
    for (int i = 0; i < 4; ++i)
      bq[i] = *(const bf16x8*)(rbase + rbB + i * 1024);
    __builtin_amdgcn_s_setprio(1);
#pragma unroll
    for (int mi = 0; mi < 4; ++mi)
#pragma unroll
      for (int ni = 0; ni < 4; ++ni)
        acc[mi][ni] = MFMA_BF16(af[mi], bq[ni], acc[mi][ni], 0, 0, 0);
    __builtin_amdgcn_s_setprio(0);
    if (kt + 2 < NKT) {
      asm volatile("s_waitcnt vmcnt(3)" ::: "memory");
    } else if (kt + 1 < NKT) {
      asm volatile("s_waitcnt vmcnt(0)" ::: "memory");
    }
    asm volatile("" ::: "memory");
    __builtin_amdgcn_s_barrier();
  }
}

// --------------------------- GEMM2 + bias (R7, unchanged) -------------------
__global__ __launch_bounds__(512, 4) void gemm2_kernel(
    const __bf16* __restrict__ hnew, const __bf16* __restrict__ fcw,
    const float* __restrict__ fcb, float* __restrict__ out) {
  const int t = threadIdx.x, wid = t >> 6, l = t & 63;
  const int wm = wid >> 1, wc = wid & 1;
  const int bid = blockIdx.x;
  const int swz = (bid & 7) * 160 + (bid >> 3);
  const size_t m0 = (size_t)(swz / 5) << 8;
  const int n0 = (swz % 5) << 7;

  __shared__ __align__(16) char lds[73728];

  f32x4 acc[4][4];
#pragma unroll
  for (int mi = 0; mi < 4; ++mi)
#pragma unroll
    for (int ni = 0; ni < 4; ++ni) acc[mi][ni] = (f32x4){0.f, 0.f, 0.f, 0.f};

  gemm_core8<16, 512>(hnew, fcw, m0, n0, lds, acc, wid, l, wm, wc);

  const int lr = l & 15, lq = l >> 4;
#pragma unroll
  for (int ni = 0; ni < 4; ++ni) {
    const int n = n0 + wc * 64 + ni * 16 + lr;
    if (n < 513) {
      const float bias = fcb[n];
#pragma unroll
      for (int mi = 0; mi < 4; ++mi) {
#pragma unroll
        for (int r = 0; r < 4; ++r) {
          const size_t m = m0 + wm * 64 + mi * 16 + lq * 4 + r;
          out[m * 513 + n] = acc[mi][ni][r] + bias;
        }
      }
    }
  }
}

// --------------------------- launch -----------------------------------------
extern "C" void kernel_launch(void* const* d_in, const int* in_sizes, int n_in,
                              void* d_out, int out_size, void* d_ws, size_t ws_size,
                              hipStream_t stream) {
  const float* x = (const float*)d_in[0];     // [64,1024,513]
  const float* h0 = (const float*)d_in[1];    // [1,64,512]
  const float* c0 = (const float*)d_in[2];    // [1,64,512]
  const float* Wih = (const float*)d_in[3];   // [2048,513]
  const float* Whh = (const float*)d_in[4];   // [2048,512]
  const float* bih = (const float*)d_in[5];   // [2048]
  const float* bhh = (const float*)d_in[6];   // [2048]
  const float* fcw = (const float*)d_in[7];   // [513,512]
  const float* fcb = (const float*)d_in[8];   // [513]
  float* out = (float*)d_out;                 // [64,1024,513]

  char* ws = (char*)d_ws;
  __bf16* xbf = (__bf16*)(ws);                 // 65536*544*2 = 71,303,168
  __bf16* wpk = (__bf16*)(ws + 71303168);      //  2048*544*2 =  2,228,224
  __bf16* fwbf = (__bf16*)(ws + 73531392);     //   640*512*2 =    655,360
  float* hb = (float*)(ws + 74186752);         //   64*2048*4 =    524,288
  __bf16* hn = (__bf16*)(ws + 74711040);       // 65536*512*2 = 67,108,864
  // total ws use: 141,819,904 bytes

  prep_kernel<<<100992, 256, 0, stream>>>(x, Wih, fcw, h0, Whh, bih, bhh,
                                          xbf, wpk, fwbf, hb);
  gemm1_kernel<<<2048, 1024, 0, stream>>>(xbf, wpk, hb, c0, hn);
  gemm2_kernel<<<1280, 512, 0, stream>>>(hn, fwbf, fcb, out);
}

// Round 16
// 369.162 us; speedup vs baseline: 1.1077x; 1.1077x over previous
//
#include <hip/hip_runtime.h>
#include <hip/hip_bf16.h>
#include <stdint.h>

// ---------------------------------------------------------------------------
// Decoder (teacher-forced, state never advances):
//   gates = x @ W_ih^T + (h0 @ W_hh^T + b_ih + b_hh)  (broadcast over t)
//   i,f,g,o = split(gates); c' = sig(f)*c0 + sig(i)*tanh(g); h' = sig(o)*tanh(c')
//   out = h' @ fc_w^T + fc_b
// Sizes: B=64, T=1024, D=513, H=512, 4H=2048.  M = B*T = 65536.
// R15: R13 config (best: 378.4us) + fragment-ordered hnew cells:
//   - hnew stored as [m-subtile][k-chunk32] 1KB cells (16 rows x 32 k,
//     lane=(kq<<4)|row, 8 k each) instead of row-major [65536][512].
//   - gemm1 epilogue: LSTM -> LDS scatter (8KB, once) -> coalesced 1KB
//     dwordx4 flush (was 16 scattered 2B stores/thread -> 32B HBM bursts).
//   - gemm2 A-stage: gld16 from cells, per-lane source = base + l*16
//     (perfectly linear; LDS content byte-identical to before).
//   prep (R13 fused) / gemm1 R4 core / gemm2 R7 core otherwise unchanged.
// ---------------------------------------------------------------------------

typedef __bf16 bf16x8 __attribute__((ext_vector_type(8)));
typedef float f32x4 __attribute__((ext_vector_type(4)));

#define MFMA_BF16 __builtin_amdgcn_mfma_f32_16x16x32_bf16

__device__ __forceinline__ void gld16(const void* gptr, void* lptr) {
  __builtin_amdgcn_global_load_lds(
      (const __attribute__((address_space(1))) void*)gptr,
      (__attribute__((address_space(3))) void*)lptr, 16, 0, 0);
}

__device__ __forceinline__ float fsigm(float x) {
  x = fminf(fmaxf(x, -30.f), 30.f);
  return __frcp_rn(1.f + __expf(-x));
}
__device__ __forceinline__ float ftanh(float x) {
  x = fminf(fmaxf(x, -15.f), 15.f);
  const float e = __expf(2.f * x);
  return (e - 1.f) * __frcp_rn(e + 1.f);
}

// --------------------------- fused prep (R13, unchanged) --------------------
__global__ __launch_bounds__(256) void prep_kernel(
    const float* __restrict__ x, const float* __restrict__ Wih,
    const float* __restrict__ fcw, const float* __restrict__ h0,
    const float* __restrict__ Whh, const float* __restrict__ bih,
    const float* __restrict__ bhh, __bf16* __restrict__ xbf,
    __bf16* __restrict__ wpk, __bf16* __restrict__ fwbf,
    float* __restrict__ hbias) {
  const int bid = blockIdx.x;
  const int t = threadIdx.x;

  if (bid < 2048) {  // ---- pack_wih
    const int p = bid;
    const int g = (p >> 4) & 3;
    const int h = ((p >> 6) << 4) + (p & 15);
    const float* src = Wih + (size_t)(g * 512 + h) * 513;
    for (int c = t * 2; c < 544; c += 512) {
      float v0 = (c < 513) ? src[c] : 0.f;
      float v1 = (c + 1 < 513) ? src[c + 1] : 0.f;
      union { __bf16 hh[2]; uint32_t u; } pk;
      pk.hh[0] = (__bf16)v0;
      pk.hh[1] = (__bf16)v1;
      *(uint32_t*)&wpk[(size_t)p * 544 + c] = pk.u;
    }
  } else if (bid < 2688) {  // ---- pack_fcw
    const int r = bid - 2048;
    const bool rv = r < 513;
    const float* src = fcw + (size_t)r * 512;
    for (int c = t * 2; c < 512; c += 512) {
      float v0 = rv ? src[c] : 0.f;
      float v1 = rv ? src[c + 1] : 0.f;
      union { __bf16 hh[2]; uint32_t u; } pk;
      pk.hh[0] = (__bf16)v0;
      pk.hh[1] = (__bf16)v1;
      *(uint32_t*)&fwbf[(size_t)r * 512 + c] = pk.u;
    }
  } else if (bid < 35456) {  // ---- hbias
    const int hb_bid = bid - 2688;
    const int w = t >> 6, l = t & 63;
    const int b = hb_bid >> 9;
    const int g = ((hb_bid & 511) << 2) | w;
    const float* hr = h0 + b * 512;
    const float* wr = Whh + (size_t)g * 512;
    float s = 0.f;
#pragma unroll
    for (int h = 0; h < 512; h += 64) s = fmaf(hr[h + l], wr[h + l], s);
#pragma unroll
    for (int off = 32; off; off >>= 1) s += __shfl_down(s, off);
    if (l == 0) hbias[b * 2048 + g] = s + bih[g] + bhh[g];
  } else {  // ---- pack_x
    const int r = bid - 35456;
    const float* src = x + (size_t)r * 513;
    for (int c = t * 2; c < 544; c += 512) {
      float v0 = (c < 513) ? src[c] : 0.f;
      float v1 = (c + 1 < 513) ? src[c + 1] : 0.f;
      union { __bf16 hh[2]; uint32_t u; } pk;
      pk.hh[0] = (__bf16)v0;
      pk.hh[1] = (__bf16)v1;
      *(uint32_t*)&xbf[(size_t)r * 544 + c] = pk.u;
    }
  }
}

// --------------------------- R4 core: 128x128, 4 waves ----------------------
// LDS: 3 buffers x (A 8KB + B 8KB) = 48KB. One barrier + vmcnt(4)/K-tile.
template <int NKT, int KSTR>
__device__ __forceinline__ void gemm_core4(
    const __bf16* __restrict__ A, const __bf16* __restrict__ B,
    size_t m0, int n0, char* lds, f32x4 (&acc)[4][4],
    int w, int l, int wm, int wc) {
  const int lr = l & 15, lq = l >> 4;
  const __bf16* ag = A + (m0 + w * 32 + lr) * KSTR + lq * 8;
  const __bf16* bg = B + (size_t)(n0 + w * 32 + lr) * KSTR + lq * 8;
  const int sdst = w * 2048;
  const int ra = wm * 4096 + l * 16;
  const int rbB = 8192 + wc * 4096 + l * 16;

#pragma unroll
  for (int p = 0; p < 2; ++p) {
    char* base = lds + p * 16384;
    gld16(ag + p * 32, base + sdst);
    gld16(ag + p * 32 + 16 * KSTR, base + sdst + 1024);
    gld16(bg + p * 32, base + 8192 + sdst);
    gld16(bg + p * 32 + 16 * KSTR, base + 8192 + sdst + 1024);
  }
  asm volatile("s_waitcnt vmcnt(4)" ::: "memory");
  __builtin_amdgcn_s_barrier();

  int rb = 0;
  for (int kt = 0; kt < NKT; ++kt) {
    char* rbase = lds + rb * 16384;
    if (kt + 2 < NKT) {
      char* wbase = lds + ((rb + 2) % 3) * 16384;
      const int kof = (kt + 2) * 32;
      gld16(ag + kof, wbase + sdst);
      gld16(ag + kof + 16 * KSTR, wbase + sdst + 1024);
      gld16(bg + kof, wbase + 8192 + sdst);
      gld16(bg + kof + 16 * KSTR, wbase + 8192 + sdst + 1024);
    }
    bf16x8 af[4], bq[4];
#pragma unroll
    for (int i = 0; i < 4; ++i)
      af[i] = *(const bf16x8*)(rbase + ra + i * 1024);
#pragma unroll
    for (int i = 0; i < 4; ++i)
      bq[i] = *(const bf16x8*)(rbase + rbB + i * 1024);
    __builtin_amdgcn_s_setprio(1);
#pragma unroll
    for (int mi = 0; mi < 4; ++mi)
#pragma unroll
      for (int ni = 0; ni < 4; ++ni)
        acc[mi][ni] = MFMA_BF16(af[mi], bq[ni], acc[mi][ni], 0, 0, 0);
    __builtin_amdgcn_s_setprio(0);
    if (kt + 2 < NKT) {
      asm volatile("s_waitcnt vmcnt(4)" ::: "memory");
    } else if (kt + 1 < NKT) {
      asm volatile("s_waitcnt vmcnt(0)" ::: "memory");
    }
    asm volatile("" ::: "memory");
    __builtin_amdgcn_s_barrier();
    rb = (rb == 2) ? 0 : rb + 1;
  }
}

// --------------------------- GEMM1 + LSTM cell (R4 + cell epilogue) ---------
// A = xbf [65536 x 544], B = wpk [2048 x 544] gate-interleaved.
// grid 8192 = 512 m-tiles x 16 n-tiles.
// Output: hnew CELLS [4096 sm][16 kc] x 1KB; cell: lane=(kq<<4)|row, 8 k.
__global__ __launch_bounds__(256, 3) void gemm1_kernel(
    const __bf16* __restrict__ xbf, const __bf16* __restrict__ wpk,
    const float* __restrict__ hbias, const float* __restrict__ c0,
    __bf16* __restrict__ hnew) {
  const int t = threadIdx.x, w = t >> 6, l = t & 63;
  const int wm = w >> 1, wc = w & 1;
  const int bid = blockIdx.x;
  const int swz = (bid & 7) * 1024 + (bid >> 3);  // XCD-contiguous
  const size_t m0 = (size_t)(swz >> 4) << 7;
  const int n0 = (swz & 15) << 7;

  __shared__ __align__(16) char lds[49152];

  f32x4 acc[4][4];
#pragma unroll
  for (int mi = 0; mi < 4; ++mi)
#pragma unroll
    for (int ni = 0; ni < 4; ++ni) acc[mi][ni] = (f32x4){0.f, 0.f, 0.f, 0.f};

  gemm_core4<17, 544>(xbf, wpk, m0, n0, lds, acc, w, l, wm, wc);

  // epilogue: lane col p = n0 + wc*64 + ni*16 + lr -> gate = ni,
  // hcol = ((n0>>6)+wc)*16 + lr; block spans 32 hcols = k-chunk kc = n0>>7.
  const int lr = l & 15, lq = l >> 4;
  const int hcol = (((n0 >> 6) + wc) << 4) + lr;
  const int b = (int)(m0 >> 10);
  const float hb0 = hbias[b * 2048 + hcol];
  const float hb1 = hbias[b * 2048 + 512 + hcol];
  const float hb2 = hbias[b * 2048 + 1024 + hcol];
  const float hb3 = hbias[b * 2048 + 1536 + hcol];
  const float c0v = c0[b * 512 + hcol];
  // LSTM -> LDS scatter in cell order: cell sm_local = wm*4+mi (1KB each),
  // lane2 = ((wc*2 + (lr>>3))<<4) | (row in subtile), byte = (lr&7)*2.
  char* stg = lds;  // K-loop done (loop ends with barrier): LDS free
  const int l2b = (wc * 2 + (lr >> 3)) << 4;
  const int byt = (lr & 7) * 2;
#pragma unroll
  for (int mi = 0; mi < 4; ++mi) {
#pragma unroll
    for (int r = 0; r < 4; ++r) {
      const float gi = acc[mi][0][r] + hb0;
      const float gf = acc[mi][1][r] + hb1;
      const float gg = acc[mi][2][r] + hb2;
      const float go = acc[mi][3][r] + hb3;
      const float cn = fsigm(gf) * c0v + fsigm(gi) * ftanh(gg);
      const float hv = fsigm(go) * ftanh(cn);
      *(__bf16*)(stg + ((wm * 4 + mi) << 10) + (l2b + lq * 4 + r) * 16 + byt) =
          (__bf16)hv;
    }
  }
  __syncthreads();
  // coalesced flush: 8 cells x 1KB -> global cells [(m0>>4)+cl][kc]
  const int kc = n0 >> 7;
  char* hnc = (char*)hnew;
#pragma unroll
  for (int p = 0; p < 2; ++p) {
    const int cl = p * 4 + (t >> 6);
    const uint4 v = *(const uint4*)(stg + cl * 1024 + (t & 63) * 16);
    *(uint4*)(hnc + ((((m0 >> 4) + cl) << 4) + kc) * 1024 + (t & 63) * 16) = v;
  }
}

// --------------------------- R7 core, A from cells (gemm2) ------------------
// A source = hnew cells: subtile s, k-chunk kt at byte (s*16+kt)*1024,
// per-lane source = cellbase + l*16 (linear). B = fwbf row-major.
// LDS: 3 buffers x (A 16KB + B 8KB) = 72KB. One barrier + vmcnt(3)/K-tile.
template <int NKT>
__device__ __forceinline__ void gemm_core8f(
    const char* __restrict__ Ac, const __bf16* __restrict__ B,
    size_t m0, int n0, char* lds, f32x4 (&acc)[4][4],
    int wid, int l, int wm, int wc) {
  const int lr = l & 15, lq = l >> 4;
  const char* ag = Ac + (((m0 >> 4) + wid) << 14) + l * 16;   // subtile wid
  const char* ag2 = ag + (size_t)(8 << 14);                   // +128 rows
  const __bf16* bg = B + (size_t)(n0 + wid * 16 + lr) * 512 + lq * 8;
  const int sdA = wid << 10;
  const int sdB = 16384 + (wid << 10);
  const int ra = (wm << 12) + l * 16;
  const int rbB = 16384 + (wc << 12) + l * 16;

#pragma unroll
  for (int p = 0; p < 2; ++p) {
    char* base = lds + p * 24576;
    gld16(ag + p * 1024, base + sdA);
    gld16(ag2 + p * 1024, base + sdA + 8192);
    gld16(bg + p * 32, base + sdB);
  }
  asm volatile("s_waitcnt vmcnt(3)" ::: "memory");
  __builtin_amdgcn_s_barrier();

#pragma unroll
  for (int kt = 0; kt < NKT; ++kt) {
    char* rbase = lds + (kt % 3) * 24576;
    if (kt + 2 < NKT) {
      char* wbase = lds + ((kt + 2) % 3) * 24576;
      gld16(ag + (kt + 2) * 1024, wbase + sdA);
      gld16(ag2 + (kt + 2) * 1024, wbase + sdA + 8192);
      gld16(bg + (kt + 2) * 32, wbase + sdB);
    }
    bf16x8 af[4], bq[4];
#pragma unroll
    for (int i = 0; i < 4; ++i)
      af[i] = *(const bf16x8*)(rbase + ra + i * 1024);
#pragma unroll
    for (int i = 0; i < 4; ++i)
      bq[i] = *(const bf16x8*)(rbase + rbB + i * 1024);
    __builtin_amdgcn_s_setprio(1);
#pragma unroll
    for (int mi = 0; mi < 4; ++mi)
#pragma unroll
      for (int ni = 0; ni < 4; ++ni)
        acc[mi][ni] = MFMA_BF16(af[mi], bq[ni], acc[mi][ni], 0, 0, 0);
    __builtin_amdgcn_s_setprio(0);
    if (kt + 2 < NKT) {
      asm volatile("s_waitcnt vmcnt(3)" ::: "memory");
    } else if (kt + 1 < NKT) {
      asm volatile("s_waitcnt vmcnt(0)" ::: "memory");
    }
    asm volatile("" ::: "memory");
    __builtin_amdgcn_s_barrier();
  }
}

// --------------------------- GEMM2 + bias -----------------------------------
// A = hnew cells, B = fwbf [640 x 512] (rows 513.. zero).
// grid 1280 = 256 m-tiles x 5 n-tiles.
__global__ __launch_bounds__(512, 4) void gemm2_kernel(
    const char* __restrict__ hnc, const __bf16* __restrict__ fcw,
    const float* __restrict__ fcb, float* __restrict__ out) {
  const int t = threadIdx.x, wid = t >> 6, l = t & 63;
  const int wm = wid >> 1, wc = wid & 1;
  const int bid = blockIdx.x;
  const int swz = (bid & 7) * 160 + (bid >> 3);
  const size_t m0 = (size_t)(swz / 5) << 8;
  const int n0 = (swz % 5) << 7;

  __shared__ __align__(16) char lds[73728];

  f32x4 acc[4][4];
#pragma unroll
  for (int mi = 0; mi < 4; ++mi)
#pragma unroll
    for (int ni = 0; ni < 4; ++ni) acc[mi][ni] = (f32x4){0.f, 0.f, 0.f, 0.f};

  gemm_core8f<16>(hnc, fcw, m0, n0, lds, acc, wid, l, wm, wc);

  const int lr = l & 15, lq = l >> 4;
#pragma unroll
  for (int ni = 0; ni < 4; ++ni) {
    const int n = n0 + wc * 64 + ni * 16 + lr;
    if (n < 513) {
      const float bias = fcb[n];
#pragma unroll
      for (int mi = 0; mi < 4; ++mi) {
#pragma unroll
        for (int r = 0; r < 4; ++r) {
          const size_t m = m0 + wm * 64 + mi * 16 + lq * 4 + r;
          out[m * 513 + n] = acc[mi][ni][r] + bias;
        }
      }
    }
  }
}

// --------------------------- launch -----------------------------------------
extern "C" void kernel_launch(void* const* d_in, const int* in_sizes, int n_in,
                              void* d_out, int out_size, void* d_ws, size_t ws_size,
                              hipStream_t stream) {
  const float* x = (const float*)d_in[0];     // [64,1024,513]
  const float* h0 = (const float*)d_in[1];    // [1,64,512]
  const float* c0 = (const float*)d_in[2];    // [1,64,512]
  const float* Wih = (const float*)d_in[3];   // [2048,513]
  const float* Whh = (const float*)d_in[4];   // [2048,512]
  const float* bih = (const float*)d_in[5];   // [2048]
  const float* bhh = (const float*)d_in[6];   // [2048]
  const float* fcw = (const float*)d_in[7];   // [513,512]
  const float* fcb = (const float*)d_in[8];   // [513]
  float* out = (float*)d_out;                 // [64,1024,513]

  char* ws = (char*)d_ws;
  __bf16* xbf = (__bf16*)(ws);                 // 65536*544*2 = 71,303,168
  __bf16* wpk = (__bf16*)(ws + 71303168);      //  2048*544*2 =  2,228,224
  __bf16* fwbf = (__bf16*)(ws + 73531392);     //   640*512*2 =    655,360
  float* hb = (float*)(ws + 74186752);         //   64*2048*4 =    524,288
  char* hn = ws + 74711040;                    // cells: 4096*16*1024 = 67,108,864
  // total ws use: 141,819,904 bytes

  prep_kernel<<<100992, 256, 0, stream>>>(x, Wih, fcw, h0, Whh, bih, bhh,
                                          xbf, wpk, fwbf, hb);
  gemm1_kernel<<<8192, 256, 0, stream>>>(xbf, wpk, hb, c0, (__bf16*)hn);
  gemm2_kernel<<<1280, 512, 0, stream>>>(hn, fwbf, fcb, out);
}

// Round 17
// 357.413 us; speedup vs baseline: 1.1441x; 1.0329x over previous
//
#include <hip/hip_runtime.h>
#include <hip/hip_bf16.h>
#include <stdint.h>

// ---------------------------------------------------------------------------
// Decoder (teacher-forced, state never advances):
//   gates = x @ W_ih^T + (h0 @ W_hh^T + b_ih + b_hh)  (broadcast over t)
//   i,f,g,o = split(gates); c' = sig(f)*c0 + sig(i)*tanh(g); h' = sig(o)*tanh(c')
//   out = h' @ fc_w^T + fc_b
// Sizes: B=64, T=1024, D=513, H=512, 4H=2048.  M = B*T = 65536.
// R16: R15 config (best: 369.2us) + gemm2 N-pad elimination:
//   - gemm2 grid 1280 -> 1024 (4 n-tiles = cols 0..511 exactly).
//   - col n=512 fused into n-tile-0 blocks as a VALU side-accumulation:
//     wc==0 waves dot their ALREADY-LOADED A fragments with fcw[512][k]
//     (bf16x8 broadcast load per k-tile), 2-shfl reduce, one store.
//   Everything else byte-identical to R15 (prep fused, gemm1 R4 core +
//   cell epilogue, gemm2 R7 core with cell A-fetch).
// ---------------------------------------------------------------------------

typedef __bf16 bf16x8 __attribute__((ext_vector_type(8)));
typedef float f32x4 __attribute__((ext_vector_type(4)));

#define MFMA_BF16 __builtin_amdgcn_mfma_f32_16x16x32_bf16

__device__ __forceinline__ void gld16(const void* gptr, void* lptr) {
  __builtin_amdgcn_global_load_lds(
      (const __attribute__((address_space(1))) void*)gptr,
      (__attribute__((address_space(3))) void*)lptr, 16, 0, 0);
}

__device__ __forceinline__ float fsigm(float x) {
  x = fminf(fmaxf(x, -30.f), 30.f);
  return __frcp_rn(1.f + __expf(-x));
}
__device__ __forceinline__ float ftanh(float x) {
  x = fminf(fmaxf(x, -15.f), 15.f);
  const float e = __expf(2.f * x);
  return (e - 1.f) * __frcp_rn(e + 1.f);
}

// --------------------------- fused prep (R13, unchanged) --------------------
__global__ __launch_bounds__(256) void prep_kernel(
    const float* __restrict__ x, const float* __restrict__ Wih,
    const float* __restrict__ fcw, const float* __restrict__ h0,
    const float* __restrict__ Whh, const float* __restrict__ bih,
    const float* __restrict__ bhh, __bf16* __restrict__ xbf,
    __bf16* __restrict__ wpk, __bf16* __restrict__ fwbf,
    float* __restrict__ hbias) {
  const int bid = blockIdx.x;
  const int t = threadIdx.x;

  if (bid < 2048) {  // ---- pack_wih
    const int p = bid;
    const int g = (p >> 4) & 3;
    const int h = ((p >> 6) << 4) + (p & 15);
    const float* src = Wih + (size_t)(g * 512 + h) * 513;
    for (int c = t * 2; c < 544; c += 512) {
      float v0 = (c < 513) ? src[c] : 0.f;
      float v1 = (c + 1 < 513) ? src[c + 1] : 0.f;
      union { __bf16 hh[2]; uint32_t u; } pk;
      pk.hh[0] = (__bf16)v0;
      pk.hh[1] = (__bf16)v1;
      *(uint32_t*)&wpk[(size_t)p * 544 + c] = pk.u;
    }
  } else if (bid < 2688) {  // ---- pack_fcw
    const int r = bid - 2048;
    const bool rv = r < 513;
    const float* src = fcw + (size_t)r * 512;
    for (int c = t * 2; c < 512; c += 512) {
      float v0 = rv ? src[c] : 0.f;
      float v1 = rv ? src[c + 1] : 0.f;
      union { __bf16 hh[2]; uint32_t u; } pk;
      pk.hh[0] = (__bf16)v0;
      pk.hh[1] = (__bf16)v1;
      *(uint32_t*)&fwbf[(size_t)r * 512 + c] = pk.u;
    }
  } else if (bid < 35456) {  // ---- hbias
    const int hb_bid = bid - 2688;
    const int w = t >> 6, l = t & 63;
    const int b = hb_bid >> 9;
    const int g = ((hb_bid & 511) << 2) | w;
    const float* hr = h0 + b * 512;
    const float* wr = Whh + (size_t)g * 512;
    float s = 0.f;
#pragma unroll
    for (int h = 0; h < 512; h += 64) s = fmaf(hr[h + l], wr[h + l], s);
#pragma unroll
    for (int off = 32; off; off >>= 1) s += __shfl_down(s, off);
    if (l == 0) hbias[b * 2048 + g] = s + bih[g] + bhh[g];
  } else {  // ---- pack_x
    const int r = bid - 35456;
    const float* src = x + (size_t)r * 513;
    for (int c = t * 2; c < 544; c += 512) {
      float v0 = (c < 513) ? src[c] : 0.f;
      float v1 = (c + 1 < 513) ? src[c + 1] : 0.f;
      union { __bf16 hh[2]; uint32_t u; } pk;
      pk.hh[0] = (__bf16)v0;
      pk.hh[1] = (__bf16)v1;
      *(uint32_t*)&xbf[(size_t)r * 544 + c] = pk.u;
    }
  }
}

// --------------------------- R4 core: 128x128, 4 waves ----------------------
// LDS: 3 buffers x (A 8KB + B 8KB) = 48KB. One barrier + vmcnt(4)/K-tile.
template <int NKT, int KSTR>
__device__ __forceinline__ void gemm_core4(
    const __bf16* __restrict__ A, const __bf16* __restrict__ B,
    size_t m0, int n0, char* lds, f32x4 (&acc)[4][4],
    int w, int l, int wm, int wc) {
  const int lr = l & 15, lq = l >> 4;
  const __bf16* ag = A + (m0 + w * 32 + lr) * KSTR + lq * 8;
  const __bf16* bg = B + (size_t)(n0 + w * 32 + lr) * KSTR + lq * 8;
  const int sdst = w * 2048;
  const int ra = wm * 4096 + l * 16;
  const int rbB = 8192 + wc * 4096 + l * 16;

#pragma unroll
  for (int p = 0; p < 2; ++p) {
    char* base = lds + p * 16384;
    gld16(ag + p * 32, base + sdst);
    gld16(ag + p * 32 + 16 * KSTR, base + sdst + 1024);
    gld16(bg + p * 32, base + 8192 + sdst);
    gld16(bg + p * 32 + 16 * KSTR, base + 8192 + sdst + 1024);
  }
  asm volatile("s_waitcnt vmcnt(4)" ::: "memory");
  __builtin_amdgcn_s_barrier();

  int rb = 0;
  for (int kt = 0; kt < NKT; ++kt) {
    char* rbase = lds + rb * 16384;
    if (kt + 2 < NKT) {
      char* wbase = lds + ((rb + 2) % 3) * 16384;
      const int kof = (kt + 2) * 32;
      gld16(ag + kof, wbase + sdst);
      gld16(ag + kof + 16 * KSTR, wbase + sdst + 1024);
      gld16(bg + kof, wbase + 8192 + sdst);
      gld16(bg + kof + 16 * KSTR, wbase + 8192 + sdst + 1024);
    }
    bf16x8 af[4], bq[4];
#pragma unroll
    for (int i = 0; i < 4; ++i)
      af[i] = *(const bf16x8*)(rbase + ra + i * 1024);
#pragma unroll
    for (int i = 0; i < 4; ++i)
      bq[i] = *(const bf16x8*)(rbase + rbB + i * 1024);
    __builtin_amdgcn_s_setprio(1);
#pragma unroll
    for (int mi = 0; mi < 4; ++mi)
#pragma unroll
      for (int ni = 0; ni < 4; ++ni)
        acc[mi][ni] = MFMA_BF16(af[mi], bq[ni], acc[mi][ni], 0, 0, 0);
    __builtin_amdgcn_s_setprio(0);
    if (kt + 2 < NKT) {
      asm volatile("s_waitcnt vmcnt(4)" ::: "memory");
    } else if (kt + 1 < NKT) {
      asm volatile("s_waitcnt vmcnt(0)" ::: "memory");
    }
    asm volatile("" ::: "memory");
    __builtin_amdgcn_s_barrier();
    rb = (rb == 2) ? 0 : rb + 1;
  }
}

// --------------------------- GEMM1 + LSTM cell (R15, unchanged) -------------
// Output: hnew CELLS [4096 sm][16 kc] x 1KB; cell: lane=(kq<<4)|row, 8 k.
__global__ __launch_bounds__(256, 3) void gemm1_kernel(
    const __bf16* __restrict__ xbf, const __bf16* __restrict__ wpk,
    const float* __restrict__ hbias, const float* __restrict__ c0,
    __bf16* __restrict__ hnew) {
  const int t = threadIdx.x, w = t >> 6, l = t & 63;
  const int wm = w >> 1, wc = w & 1;
  const int bid = blockIdx.x;
  const int swz = (bid & 7) * 1024 + (bid >> 3);  // XCD-contiguous
  const size_t m0 = (size_t)(swz >> 4) << 7;
  const int n0 = (swz & 15) << 7;

  __shared__ __align__(16) char lds[49152];

  f32x4 acc[4][4];
#pragma unroll
  for (int mi = 0; mi < 4; ++mi)
#pragma unroll
    for (int ni = 0; ni < 4; ++ni) acc[mi][ni] = (f32x4){0.f, 0.f, 0.f, 0.f};

  gemm_core4<17, 544>(xbf, wpk, m0, n0, lds, acc, w, l, wm, wc);

  const int lr = l & 15, lq = l >> 4;
  const int hcol = (((n0 >> 6) + wc) << 4) + lr;
  const int b = (int)(m0 >> 10);
  const float hb0 = hbias[b * 2048 + hcol];
  const float hb1 = hbias[b * 2048 + 512 + hcol];
  const float hb2 = hbias[b * 2048 + 1024 + hcol];
  const float hb3 = hbias[b * 2048 + 1536 + hcol];
  const float c0v = c0[b * 512 + hcol];
  char* stg = lds;  // K-loop done (loop ends with barrier): LDS free
  const int l2b = (wc * 2 + (lr >> 3)) << 4;
  const int byt = (lr & 7) * 2;
#pragma unroll
  for (int mi = 0; mi < 4; ++mi) {
#pragma unroll
    for (int r = 0; r < 4; ++r) {
      const float gi = acc[mi][0][r] + hb0;
      const float gf = acc[mi][1][r] + hb1;
      const float gg = acc[mi][2][r] + hb2;
      const float go = acc[mi][3][r] + hb3;
      const float cn = fsigm(gf) * c0v + fsigm(gi) * ftanh(gg);
      const float hv = fsigm(go) * ftanh(cn);
      *(__bf16*)(stg + ((wm * 4 + mi) << 10) + (l2b + lq * 4 + r) * 16 + byt) =
          (__bf16)hv;
    }
  }
  __syncthreads();
  const int kc = n0 >> 7;
  char* hnc = (char*)hnew;
#pragma unroll
  for (int p = 0; p < 2; ++p) {
    const int cl = p * 4 + (t >> 6);
    const uint4 v = *(const uint4*)(stg + cl * 1024 + (t & 63) * 16);
    *(uint4*)(hnc + ((((m0 >> 4) + cl) << 4) + kc) * 1024 + (t & 63) * 16) = v;
  }
}

// --------------------------- R7 core, A from cells + col-512 fusion ---------
// A source = hnew cells; per-lane source = cellbase + l*16 (linear).
// DO512 (ntile-0, wc==0 waves): side-accumulate acc512[mi] += af.w512 per
// k-tile (A frags already in registers; w512 is a 16-lane-broadcast load).
template <int NKT>
__device__ __forceinline__ void gemm_core8f(
    const char* __restrict__ Ac, const __bf16* __restrict__ B,
    size_t m0, int n0, char* lds, f32x4 (&acc)[4][4], float (&acc512)[4],
    bool do512, int wid, int l, int wm, int wc) {
  const int lr = l & 15, lq = l >> 4;
  const char* ag = Ac + (((m0 >> 4) + wid) << 14) + l * 16;   // subtile wid
  const char* ag2 = ag + (size_t)(8 << 14);                   // +128 rows
  const __bf16* bg = B + (size_t)(n0 + wid * 16 + lr) * 512 + lq * 8;
  const __bf16* w512p = B + (size_t)512 * 512 + lq * 8;       // fcw row 512
  const int sdA = wid << 10;
  const int sdB = 16384 + (wid << 10);
  const int ra = (wm << 12) + l * 16;
  const int rbB = 16384 + (wc << 12) + l * 16;

#pragma unroll
  for (int p = 0; p < 2; ++p) {
    char* base = lds + p * 24576;
    gld16(ag + p * 1024, base + sdA);
    gld16(ag2 + p * 1024, base + sdA + 8192);
    gld16(bg + p * 32, base + sdB);
  }
  asm volatile("s_waitcnt vmcnt(3)" ::: "memory");
  __builtin_amdgcn_s_barrier();

#pragma unroll
  for (int kt = 0; kt < NKT; ++kt) {
    char* rbase = lds + (kt % 3) * 24576;
    if (kt + 2 < NKT) {
      char* wbase = lds + ((kt + 2) % 3) * 24576;
      gld16(ag + (kt + 2) * 1024, wbase + sdA);
      gld16(ag2 + (kt + 2) * 1024, wbase + sdA + 8192);
      gld16(bg + (kt + 2) * 32, wbase + sdB);
    }
    bf16x8 af[4], bq[4];
#pragma unroll
    for (int i = 0; i < 4; ++i)
      af[i] = *(const bf16x8*)(rbase + ra + i * 1024);
#pragma unroll
    for (int i = 0; i < 4; ++i)
      bq[i] = *(const bf16x8*)(rbase + rbB + i * 1024);
    if (do512) {  // block- and wave-uniform branch
      const bf16x8 wv = *(const bf16x8*)(w512p + kt * 32);
#pragma unroll
      for (int mi = 0; mi < 4; ++mi)
#pragma unroll
        for (int j = 0; j < 8; ++j)
          acc512[mi] = fmaf((float)af[mi][j], (float)wv[j], acc512[mi]);
    }
    __builtin_amdgcn_s_setprio(1);
#pragma unroll
    for (int mi = 0; mi < 4; ++mi)
#pragma unroll
      for (int ni = 0; ni < 4; ++ni)
        acc[mi][ni] = MFMA_BF16(af[mi], bq[ni], acc[mi][ni], 0, 0, 0);
    __builtin_amdgcn_s_setprio(0);
    if (kt + 2 < NKT) {
      asm volatile("s_waitcnt vmcnt(3)" ::: "memory");
    } else if (kt + 1 < NKT) {
      asm volatile("s_waitcnt vmcnt(0)" ::: "memory");
    }
    asm volatile("" ::: "memory");
    __builtin_amdgcn_s_barrier();
  }
}

// --------------------------- GEMM2 + bias -----------------------------------
// A = hnew cells, B = fwbf. grid 1024 = 256 m-tiles x 4 n-tiles (cols 0..511).
// Col n=512 computed by ntile-0 blocks via the fused side-accumulation.
__global__ __launch_bounds__(512, 4) void gemm2_kernel(
    const char* __restrict__ hnc, const __bf16* __restrict__ fcw,
    const float* __restrict__ fcb, float* __restrict__ out) {
  const int t = threadIdx.x, wid = t >> 6, l = t & 63;
  const int wm = wid >> 1, wc = wid & 1;
  const int bid = blockIdx.x;
  const int swz = (bid & 7) * 128 + (bid >> 3);   // 1024 blocks
  const size_t m0 = (size_t)(swz >> 2) << 8;
  const int ntile = swz & 3;
  const int n0 = ntile << 7;
  const bool do512 = (ntile == 0) && (wc == 0);

  __shared__ __align__(16) char lds[73728];

  f32x4 acc[4][4];
  float acc512[4] = {0.f, 0.f, 0.f, 0.f};
#pragma unroll
  for (int mi = 0; mi < 4; ++mi)
#pragma unroll
    for (int ni = 0; ni < 4; ++ni) acc[mi][ni] = (f32x4){0.f, 0.f, 0.f, 0.f};

  gemm_core8f<16>(hnc, fcw, m0, n0, lds, acc, acc512, do512, wid, l, wm, wc);

  const int lr = l & 15, lq = l >> 4;
#pragma unroll
  for (int ni = 0; ni < 4; ++ni) {
    const int n = n0 + wc * 64 + ni * 16 + lr;
    const float bias = fcb[n];
#pragma unroll
    for (int mi = 0; mi < 4; ++mi) {
#pragma unroll
      for (int r = 0; r < 4; ++r) {
        const size_t m = m0 + wm * 64 + mi * 16 + lq * 4 + r;
        out[m * 513 + n] = acc[mi][ni][r] + bias;
      }
    }
  }
  if (do512) {  // reduce k-slices (lanes lr, 16+lr, 32+lr, 48+lr) and store
    const float b512 = fcb[512];
#pragma unroll
    for (int mi = 0; mi < 4; ++mi) {
      float s = acc512[mi];
      s += __shfl_down(s, 32);
      s += __shfl_down(s, 16);
      if (lq == 0) {
        const size_t m = m0 + (wm * 4 + mi) * 16 + lr;
        out[m * 513 + 512] = s + b512;
      }
    }
  }
}

// --------------------------- launch -----------------------------------------
extern "C" void kernel_launch(void* const* d_in, const int* in_sizes, int n_in,
                              void* d_out, int out_size, void* d_ws, size_t ws_size,
                              hipStream_t stream) {
  const float* x = (const float*)d_in[0];     // [64,1024,513]
  const float* h0 = (const float*)d_in[1];    // [1,64,512]
  const float* c0 = (const float*)d_in[2];    // [1,64,512]
  const float* Wih = (const float*)d_in[3];   // [2048,513]
  const float* Whh = (const float*)d_in[4];   // [2048,512]
  const float* bih = (const float*)d_in[5];   // [2048]
  const float* bhh = (const float*)d_in[6];   // [2048]
  const float* fcw = (const float*)d_in[7];   // [513,512]
  const float* fcb = (const float*)d_in[8];   // [513]
  float* out = (float*)d_out;                 // [64,1024,513]

  char* ws = (char*)d_ws;
  __bf16* xbf = (__bf16*)(ws);                 // 65536*544*2 = 71,303,168
  __bf16* wpk = (__bf16*)(ws + 71303168);      //  2048*544*2 =  2,228,224
  __bf16* fwbf = (__bf16*)(ws + 73531392);     //   640*512*2 =    655,360
  float* hb = (float*)(ws + 74186752);         //   64*2048*4 =    524,288
  char* hn = ws + 74711040;                    // cells: 4096*16*1024 = 67,108,864
  // total ws use: 141,819,904 bytes

  prep_kernel<<<100992, 256, 0, stream>>>(x, Wih, fcw, h0, Whh, bih, bhh,
                                          xbf, wpk, fwbf, hb);
  gemm1_kernel<<<8192, 256, 0, stream>>>(xbf, wpk, hb, c0, (__bf16*)hn);
  gemm2_kernel<<<1024, 512, 0, stream>>>(hn, fwbf, fcb, out);
}